// Round 10
// baseline (207.561 us; speedup 1.0000x reference)
//
#include <hip/hip_runtime.h>
#include <math.h>

// Problem constants (fixed by reference setup_inputs)
#define BSZ 4096   // B
#define NROW 8192  // N = 2B
#define DIM 128    // D
#define LOG2E10 14.426950408889634f   // 10 / ln(2): exp(10x) = exp2(x * this)

typedef __attribute__((ext_vector_type(8))) short bf16x8;   // 8 bf16 = 4 VGPRs
typedef __attribute__((ext_vector_type(4))) float f32x4;    // MFMA acc

// ws layout (in floats):
//   pnh   [0, N*D/2)      normalized rows, bf16, LINEAR (2 MB) — exact math side
//   pnsw  [+N*D/2)        swizzled copy, PRE-SCALED by sqrt(10/ln2): used by
//                         BOTH A and B sides (scale enters twice -> acc =
//                         sim*10/ln2 straight out of the MFMA)
//   g     [+256)          label-sum vectors g0,g1 (fp32, atomically built)
//   cnt   [+2)            label counts in y2
//   misc  [+2)            [0]=loss accumulator, [1]=completion counter
//   spart [+64*N)         partial exp row-sums, slice-major [slice*N+row]
#define PNH_F     (NROW * DIM / 2)
#define G_OFF     (2 * PNH_F)
#define CNT_OFF   (G_OFF + 256)
#define MISC_OFF  (CNT_OFF + 2)
#define SPART_OFF (G_OFF + 512)

__device__ __forceinline__ unsigned short f2bf(float f) {  // RNE
    unsigned u = __float_as_uint(f);
    return (unsigned short)((u + 0x7FFF + ((u >> 16) & 1)) >> 16);
}

// ------ Kernel 1: row normalization -> bf16 (wave per row) + zero g/misc ---
__global__ void k_norm(const float* __restrict__ zi, const float* __restrict__ zj,
                       unsigned* __restrict__ pnh, unsigned* __restrict__ pnsw,
                       float* __restrict__ g, float* __restrict__ misc) {
    int tid  = threadIdx.x;
    if (blockIdx.x == 0) {
        g[tid] = 0.f;                        // zero g before k_colsum's atomics
        if (tid == 0) { misc[0] = 0.f; ((unsigned*)misc)[1] = 0u; }
    }
    int wave = tid >> 6, lane = tid & 63;
    int row  = blockIdx.x * 4 + wave;
    const float* src = (row < BSZ) ? (zi + (size_t)row * DIM)
                                   : (zj + (size_t)(row - BSZ) * DIM);
    float2 v = ((const float2*)src)[lane];
    float ss = v.x * v.x + v.y * v.y;
    #pragma unroll
    for (int m = 32; m; m >>= 1) ss += __shfl_xor(ss, m, 64);
    float inv = 1.0f / fmaxf(sqrtf(ss), 1e-8f);
    float n0 = v.x * inv, n1 = v.y * inv;
    pnh[(size_t)row * 64 + lane] = (unsigned)f2bf(n0) | ((unsigned)f2bf(n1) << 16);
    const float s = sqrtf(LOG2E10);          // scale enters twice in A.B
    unsigned packS = (unsigned)f2bf(n0 * s) | ((unsigned)f2bf(n1 * s) << 16);
    int j = lane >> 2;                       // 16B chunk index (4 uints each)
    int sw = ((j ^ (row & 15)) << 2) | (lane & 3);
    pnsw[(size_t)row * 64 + sw] = packS;
}

// ---- Kernel 2: label-sum vectors g0/g1, coalesced row-major + atomics ----
__global__ void k_colsum(const unsigned* __restrict__ pnh, const int* __restrict__ y,
                         float* __restrict__ g, float* __restrict__ cnt) {
    __shared__ float red[4][4][64];   // [rowgrp][{s0a,s0b,s1a,s1b}][d2]
    int tid = threadIdx.x;
    if (blockIdx.x < 128) {
        int d2 = tid & 63;            // uint index: holds d = 2*d2, 2*d2+1
        int rg = tid >> 6;            // 0..3
        int row0 = blockIdx.x * 64 + rg * 16;
        float s0a = 0.f, s0b = 0.f, s1a = 0.f, s1b = 0.f;
        #pragma unroll 4
        for (int i = 0; i < 16; ++i) {
            int r = row0 + i;
            unsigned u = pnh[(size_t)r * 64 + d2];
            float va = __uint_as_float(u << 16);
            float vb = __uint_as_float(u & 0xFFFF0000u);
            if (y[r & (BSZ - 1)]) { s1a += va; s1b += vb; }
            else                  { s0a += va; s0b += vb; }
        }
        red[rg][0][d2] = s0a; red[rg][1][d2] = s0b;
        red[rg][2][d2] = s1a; red[rg][3][d2] = s1b;
        __syncthreads();
        int lab = tid >> 7, d = tid & 127;
        int which = lab * 2 + (d & 1), dd2 = d >> 1;
        float s = red[0][which][dd2] + red[1][which][dd2]
                + red[2][which][dd2] + red[3][which][dd2];
        atomicAdd(&g[lab * DIM + d], s);
    } else {
        __shared__ float r0[256];
        float c = 0.f;
        for (int r = tid; r < BSZ; r += 256) c += (float)y[r];
        r0[tid] = c;
        __syncthreads();
        for (int s = 128; s; s >>= 1) {
            if (tid < s) r0[tid] += r0[tid + s];
            __syncthreads();
        }
        if (tid == 0) { cnt[1] = 2.0f * r0[0]; cnt[0] = (float)NROW - 2.0f * r0[0]; }
    }
}

// ---- Kernel 3: SYMMETRIC bf16 MFMA exp-GEMM, upper triangle only ---------
// Exactly 2080 blocks; linear bid -> (ti,tj) via closed-form triangular
// decode (boundary discriminants 16641-8k are perfect squares (129-2ti)^2,
// exact in fp32; +-1 correction guards the irrational interiors).
// Block = 128x128 tile, 4 waves x (32 rows x 128 cols). A and B fragments
// both come from the single pre-scaled pnsw (2 MB, L2-resident); B tile
// additionally staged once into 32 KB LDS. Epilogue = bare exp2f.
// rs (rows of ti) -> slice tj; cs (rows of tj) -> slice ti; diag: rs only.
__global__ __launch_bounds__(256, 4)
void k_expsum(const unsigned short* __restrict__ pnsw, float* __restrict__ spart) {
    int k = blockIdx.x;
    float disc = sqrtf((float)(16641 - 8 * k));
    int ti = (int)((129.0f - disc) * 0.5f);
    int off = ti * (129 - ti) / 2;
    if (off > k) { --ti; off = ti * (129 - ti) / 2; }
    else { int off2 = (ti + 1) * (128 - ti) / 2; if (off2 <= k) { ti++; off = off2; } }
    int tj = ti + (k - off);

    __shared__ short bt[128 * 128];          // 32 KB B tile (rows of tile tj)
    __shared__ float rs_t[128];              // row sums of tile ti
    __shared__ float cs_p[4][128];           // per-wave col-sum partials
    int tid  = threadIdx.x;
    int lane = tid & 63;
    int w    = tid >> 6;
    int l15 = lane & 15, q = lane >> 4;
    bool isDiag = (ti == tj);
    int rwb = ti * 128 + w * 32;             // this wave's 32 rows

    // stage B tile: linear 32 KB copy (source pre-swizzled)
    {
        const float4* src = (const float4*)(pnsw + (size_t)tj * 128 * DIM);
        float4* dst = (float4*)bt;
        #pragma unroll
        for (int i = 0; i < 8; ++i)
            dst[tid + 256 * i] = src[tid + 256 * i];
    }

    // A fragments: lane holds A[m=l15][k=q*8+j], swizzled chunk (ks*4+q)^l15
    bf16x8 a[2][4];
    #pragma unroll
    for (int rf = 0; rf < 2; ++rf) {
        const unsigned short* ab = pnsw + (size_t)(rwb + rf * 16 + l15) * DIM;
        #pragma unroll
        for (int ks = 0; ks < 4; ++ks)
            a[rf][ks] = *(const bf16x8*)(ab + (((ks * 4 + q) ^ l15) << 3));
    }

    float rs[2][4], cs[8];
    #pragma unroll
    for (int rf = 0; rf < 2; ++rf)
        #pragma unroll
        for (int e = 0; e < 4; ++e) rs[rf][e] = 0.f;
    #pragma unroll
    for (int t = 0; t < 8; ++t) cs[t] = 0.f;

    __syncthreads();                         // B tile ready

    #pragma unroll
    for (int t = 0; t < 8; ++t) {            // 8 col-16 subtiles
        bf16x8 b[4];
        #pragma unroll
        for (int ks = 0; ks < 4; ++ks)
            b[ks] = *(const bf16x8*)(bt + (t * 16 + l15) * 128 + (((ks * 4 + q) ^ l15) << 3));

        f32x4 acc[2];
        acc[0] = (f32x4){0.f, 0.f, 0.f, 0.f};
        acc[1] = (f32x4){0.f, 0.f, 0.f, 0.f};
        #pragma unroll
        for (int ks = 0; ks < 4; ++ks) {
            acc[0] = __builtin_amdgcn_mfma_f32_16x16x32_bf16(a[0][ks], b[ks], acc[0], 0, 0, 0);
            acc[1] = __builtin_amdgcn_mfma_f32_16x16x32_bf16(a[1][ks], b[ks], acc[1], 0, 0, 0);
        }

        // acc already = sim*10/ln2 (sqrt-scale on both operands)
        if (isDiag && ((unsigned)(t * 16 - w * 32) < 32u)) {
            int col = tj * 128 + t * 16 + l15;
            #pragma unroll
            for (int rf = 0; rf < 2; ++rf)
                #pragma unroll
                for (int e = 0; e < 4; ++e) {
                    int row = rwb + rf * 16 + q * 4 + e;   // C-layout row
                    float ex = exp2f(acc[rf][e]);
                    if (row == col) ex = 0.f;
                    rs[rf][e] += ex; cs[t] += ex;
                }
        } else {
            #pragma unroll
            for (int rf = 0; rf < 2; ++rf)
                #pragma unroll
                for (int e = 0; e < 4; ++e) {
                    float ex = exp2f(acc[rf][e]);
                    rs[rf][e] += ex; cs[t] += ex;
                }
        }
    }

    // rs: reduce over the 16 cols held across l15 lanes (per-wave region)
    #pragma unroll
    for (int rf = 0; rf < 2; ++rf)
        #pragma unroll
        for (int e = 0; e < 4; ++e) {
            float v = rs[rf][e];
            v += __shfl_xor(v, 1, 16);
            v += __shfl_xor(v, 2, 16);
            v += __shfl_xor(v, 4, 16);
            v += __shfl_xor(v, 8, 16);
            if (l15 == 0) rs_t[w * 32 + rf * 16 + q * 4 + e] = v;
        }
    // cs: reduce over the 4 quads (rows) -> lanes 0..15 hold col partials
    #pragma unroll
    for (int t = 0; t < 8; ++t) {
        float v = cs[t];
        v += __shfl_xor(v, 16, 64);
        v += __shfl_xor(v, 32, 64);
        if (q == 0) cs_p[w][t * 16 + l15] = v;
    }
    __syncthreads();

    // coalesced 512 B stores into block-private slice runs
    if (tid < 128) {
        spart[(size_t)tj * NROW + ti * 128 + tid] = rs_t[tid];
    } else if (!isDiag) {
        int c = tid - 128;
        float v = cs_p[0][c] + cs_p[1][c] + cs_p[2][c] + cs_p[3][c];
        spart[(size_t)ti * NROW + tj * 128 + c] = v;
    }
}

// --- Kernel 4: per-row finalize + full device reduction (last block -> out) -
__global__ void k_finalize(const unsigned* __restrict__ pnh, const float* __restrict__ spart,
                           const float* __restrict__ g, const float* __restrict__ cnt,
                           const int* __restrict__ y, float* __restrict__ misc,
                           float* __restrict__ out) {
    __shared__ float red[4];
    int tid = threadIdx.x, wv = tid >> 6, lane = tid & 63;
    int row = blockIdx.x * 4 + wv;
    int lab = y[row & (BSZ - 1)];
    unsigned u = pnh[(size_t)row * 64 + lane];
    float p0 = __uint_as_float(u << 16);
    float p1 = __uint_as_float(u & 0xFFFF0000u);
    float2 gv = ((const float2*)(g + lab * DIM))[lane];
    float dg = p0 * gv.x + p1 * gv.y;
    float ds = p0 * p0 + p1 * p1;
    float sp = spart[(size_t)lane * NROW + row];   // lane = slice (L2-resident)
    #pragma unroll
    for (int m = 32; m; m >>= 1) {
        dg += __shfl_xor(dg, m, 64);
        ds += __shfl_xor(ds, m, 64);
        sp += __shfl_xor(sp, m, 64);
    }
    if (lane == 0) {
        float C = cnt[lab] - 1.0f;           // pos count excludes self
        float P = (dg - ds) * 10.0f;         // sum of sims over positives
        red[wv] = logf(sp) - P / C;          // -(mean log prob pos)
    }
    __syncthreads();
    if (tid == 0) {
        float v = red[0] + red[1] + red[2] + red[3];
        atomicAdd(&misc[0], v);              // device-scope
        __threadfence();
        unsigned old = atomicAdd((unsigned*)&misc[1], 1u);
        if (old == gridDim.x - 1) {          // all contributions in
            __threadfence();
            out[0] = atomicAdd(&misc[0], 0.0f);   // coherent final read
        }
    }
}

extern "C" void kernel_launch(void* const* d_in, const int* in_sizes, int n_in,
                              void* d_out, int out_size, void* d_ws, size_t ws_size,
                              hipStream_t stream) {
    const float* zi = (const float*)d_in[0];
    const float* zj = (const float*)d_in[1];
    const int*   y  = (const int*)d_in[2];
    float* out = (float*)d_out;
    float* ws  = (float*)d_ws;

    unsigned* pnh  = (unsigned*)ws;                 // linear, unscaled
    unsigned* pnsw = (unsigned*)(ws + PNH_F);       // swizzled, x sqrt(10/ln2)
    float* g     = ws + G_OFF;
    float* cnt   = ws + CNT_OFF;
    float* misc  = ws + MISC_OFF;
    float* spart = ws + SPART_OFF;

    k_norm<<<NROW / 4, 256, 0, stream>>>(zi, zj, pnh, pnsw, g, misc);
    k_colsum<<<129, 256, 0, stream>>>(pnh, y, g, cnt);
    k_expsum<<<2080, 256, 0, stream>>>((const unsigned short*)pnsw, spart);
    k_finalize<<<NROW / 4, 256, 0, stream>>>(pnh, spart, g, cnt, y, misc, out);
}

// Round 11
// 97.236 us; speedup vs baseline: 2.1346x; 2.1346x over previous
//
#include <hip/hip_runtime.h>
#include <math.h>

// Problem constants (fixed by reference setup_inputs)
#define BSZ 4096   // B
#define NROW 8192  // N = 2B
#define DIM 128    // D
#define LOG2E10 14.426950408889634f   // 10 / ln(2): exp(10x) = exp2(x * this)

typedef __attribute__((ext_vector_type(8))) short bf16x8;   // 8 bf16 = 4 VGPRs
typedef __attribute__((ext_vector_type(4))) float f32x4;    // MFMA acc

// ws layout (in floats):
//   pnh   [0, N*D/2)      normalized rows, bf16, LINEAR (2 MB) — exact math side
//   pnsw  [+N*D/2)        swizzled copy, PRE-SCALED by sqrt(10/ln2): used by
//                         BOTH A and B sides (scale enters twice -> acc =
//                         sim*10/ln2 straight out of the MFMA)
//   g     [+256)          label-sum vectors g0,g1 (fp32, atomically built)
//   cnt   [+2)            label counts in y2
//   spart [+64*N)         partial exp row-sums, slice-major [slice*N+row]
//   part  [+2048)         per-block loss partials (round-10 lesson: contended
//                         single-word atomics serialize at ~60ns -> 124us;
//                         private stores + tiny reduce kernel instead)
#define PNH_F     (NROW * DIM / 2)
#define G_OFF     (2 * PNH_F)
#define CNT_OFF   (G_OFF + 256)
#define SPART_OFF (G_OFF + 512)
#define PART_OFF  (SPART_OFF + 64 * NROW)

__device__ __forceinline__ unsigned short f2bf(float f) {  // RNE
    unsigned u = __float_as_uint(f);
    return (unsigned short)((u + 0x7FFF + ((u >> 16) & 1)) >> 16);
}

// ------ Kernel 1: row normalization -> bf16 (wave per row) + zero g -------
__global__ void k_norm(const float* __restrict__ zi, const float* __restrict__ zj,
                       unsigned* __restrict__ pnh, unsigned* __restrict__ pnsw,
                       float* __restrict__ g) {
    int tid  = threadIdx.x;
    if (blockIdx.x == 0) g[tid] = 0.f;      // zero g before k_colsum's atomics
    int wave = tid >> 6, lane = tid & 63;
    int row  = blockIdx.x * 4 + wave;
    const float* src = (row < BSZ) ? (zi + (size_t)row * DIM)
                                   : (zj + (size_t)(row - BSZ) * DIM);
    float2 v = ((const float2*)src)[lane];
    float ss = v.x * v.x + v.y * v.y;
    #pragma unroll
    for (int m = 32; m; m >>= 1) ss += __shfl_xor(ss, m, 64);
    float inv = 1.0f / fmaxf(sqrtf(ss), 1e-8f);
    float n0 = v.x * inv, n1 = v.y * inv;
    pnh[(size_t)row * 64 + lane] = (unsigned)f2bf(n0) | ((unsigned)f2bf(n1) << 16);
    const float s = sqrtf(LOG2E10);          // scale enters twice in A.B
    unsigned packS = (unsigned)f2bf(n0 * s) | ((unsigned)f2bf(n1 * s) << 16);
    int j = lane >> 2;                       // 16B chunk index (4 uints each)
    int sw = ((j ^ (row & 15)) << 2) | (lane & 3);
    pnsw[(size_t)row * 64 + sw] = packS;
}

// ---- Kernel 2: label-sum vectors g0/g1, coalesced row-major + atomics ----
__global__ void k_colsum(const unsigned* __restrict__ pnh, const int* __restrict__ y,
                         float* __restrict__ g, float* __restrict__ cnt) {
    __shared__ float red[4][4][64];   // [rowgrp][{s0a,s0b,s1a,s1b}][d2]
    int tid = threadIdx.x;
    if (blockIdx.x < 128) {
        int d2 = tid & 63;            // uint index: holds d = 2*d2, 2*d2+1
        int rg = tid >> 6;            // 0..3
        int row0 = blockIdx.x * 64 + rg * 16;
        float s0a = 0.f, s0b = 0.f, s1a = 0.f, s1b = 0.f;
        #pragma unroll 4
        for (int i = 0; i < 16; ++i) {
            int r = row0 + i;
            unsigned u = pnh[(size_t)r * 64 + d2];
            float va = __uint_as_float(u << 16);
            float vb = __uint_as_float(u & 0xFFFF0000u);
            if (y[r & (BSZ - 1)]) { s1a += va; s1b += vb; }
            else                  { s0a += va; s0b += vb; }
        }
        red[rg][0][d2] = s0a; red[rg][1][d2] = s0b;
        red[rg][2][d2] = s1a; red[rg][3][d2] = s1b;
        __syncthreads();
        int lab = tid >> 7, d = tid & 127;
        int which = lab * 2 + (d & 1), dd2 = d >> 1;
        float s = red[0][which][dd2] + red[1][which][dd2]
                + red[2][which][dd2] + red[3][which][dd2];
        atomicAdd(&g[lab * DIM + d], s);
    } else {
        __shared__ float r0[256];
        float c = 0.f;
        for (int r = tid; r < BSZ; r += 256) c += (float)y[r];
        r0[tid] = c;
        __syncthreads();
        for (int s = 128; s; s >>= 1) {
            if (tid < s) r0[tid] += r0[tid + s];
            __syncthreads();
        }
        if (tid == 0) { cnt[1] = 2.0f * r0[0]; cnt[0] = (float)NROW - 2.0f * r0[0]; }
    }
}

// ---- Kernel 3: SYMMETRIC bf16 MFMA exp-GEMM, upper triangle only ---------
// Exactly 2080 blocks; linear bid -> (ti,tj) via closed-form triangular
// decode (boundary discriminants 16641-8k are perfect squares (129-2ti)^2,
// exact in fp32; +-1 correction guards the irrational interiors).
// Block = 128x128 tile, 4 waves x (32 rows x 128 cols). A and B fragments
// both come from the single pre-scaled pnsw (2 MB, L2-resident); B tile
// additionally staged once into 32 KB LDS. Epilogue = bare exp2f.
// rs (rows of ti) -> slice tj; cs (rows of tj) -> slice ti; diag: rs only.
__global__ __launch_bounds__(256, 4)
void k_expsum(const unsigned short* __restrict__ pnsw, float* __restrict__ spart) {
    int k = blockIdx.x;
    float disc = sqrtf((float)(16641 - 8 * k));
    int ti = (int)((129.0f - disc) * 0.5f);
    int off = ti * (129 - ti) / 2;
    if (off > k) { --ti; off = ti * (129 - ti) / 2; }
    else { int off2 = (ti + 1) * (128 - ti) / 2; if (off2 <= k) { ti++; off = off2; } }
    int tj = ti + (k - off);

    __shared__ short bt[128 * 128];          // 32 KB B tile (rows of tile tj)
    __shared__ float rs_t[128];              // row sums of tile ti
    __shared__ float cs_p[4][128];           // per-wave col-sum partials
    int tid  = threadIdx.x;
    int lane = tid & 63;
    int w    = tid >> 6;
    int l15 = lane & 15, q = lane >> 4;
    bool isDiag = (ti == tj);
    int rwb = ti * 128 + w * 32;             // this wave's 32 rows

    // stage B tile: linear 32 KB copy (source pre-swizzled)
    {
        const float4* src = (const float4*)(pnsw + (size_t)tj * 128 * DIM);
        float4* dst = (float4*)bt;
        #pragma unroll
        for (int i = 0; i < 8; ++i)
            dst[tid + 256 * i] = src[tid + 256 * i];
    }

    // A fragments: lane holds A[m=l15][k=q*8+j], swizzled chunk (ks*4+q)^l15
    bf16x8 a[2][4];
    #pragma unroll
    for (int rf = 0; rf < 2; ++rf) {
        const unsigned short* ab = pnsw + (size_t)(rwb + rf * 16 + l15) * DIM;
        #pragma unroll
        for (int ks = 0; ks < 4; ++ks)
            a[rf][ks] = *(const bf16x8*)(ab + (((ks * 4 + q) ^ l15) << 3));
    }

    float rs[2][4], cs[8];
    #pragma unroll
    for (int rf = 0; rf < 2; ++rf)
        #pragma unroll
        for (int e = 0; e < 4; ++e) rs[rf][e] = 0.f;
    #pragma unroll
    for (int t = 0; t < 8; ++t) cs[t] = 0.f;

    __syncthreads();                         // B tile ready

    #pragma unroll
    for (int t = 0; t < 8; ++t) {            // 8 col-16 subtiles
        bf16x8 b[4];
        #pragma unroll
        for (int ks = 0; ks < 4; ++ks)
            b[ks] = *(const bf16x8*)(bt + (t * 16 + l15) * 128 + (((ks * 4 + q) ^ l15) << 3));

        f32x4 acc[2];
        acc[0] = (f32x4){0.f, 0.f, 0.f, 0.f};
        acc[1] = (f32x4){0.f, 0.f, 0.f, 0.f};
        #pragma unroll
        for (int ks = 0; ks < 4; ++ks) {
            acc[0] = __builtin_amdgcn_mfma_f32_16x16x32_bf16(a[0][ks], b[ks], acc[0], 0, 0, 0);
            acc[1] = __builtin_amdgcn_mfma_f32_16x16x32_bf16(a[1][ks], b[ks], acc[1], 0, 0, 0);
        }

        // acc already = sim*10/ln2 (sqrt-scale on both operands)
        if (isDiag && ((unsigned)(t * 16 - w * 32) < 32u)) {
            int col = tj * 128 + t * 16 + l15;
            #pragma unroll
            for (int rf = 0; rf < 2; ++rf)
                #pragma unroll
                for (int e = 0; e < 4; ++e) {
                    int row = rwb + rf * 16 + q * 4 + e;   // C-layout row
                    float ex = exp2f(acc[rf][e]);
                    if (row == col) ex = 0.f;
                    rs[rf][e] += ex; cs[t] += ex;
                }
        } else {
            #pragma unroll
            for (int rf = 0; rf < 2; ++rf)
                #pragma unroll
                for (int e = 0; e < 4; ++e) {
                    float ex = exp2f(acc[rf][e]);
                    rs[rf][e] += ex; cs[t] += ex;
                }
        }
    }

    // rs: reduce over the 16 cols held across l15 lanes (per-wave region)
    #pragma unroll
    for (int rf = 0; rf < 2; ++rf)
        #pragma unroll
        for (int e = 0; e < 4; ++e) {
            float v = rs[rf][e];
            v += __shfl_xor(v, 1, 16);
            v += __shfl_xor(v, 2, 16);
            v += __shfl_xor(v, 4, 16);
            v += __shfl_xor(v, 8, 16);
            if (l15 == 0) rs_t[w * 32 + rf * 16 + q * 4 + e] = v;
        }
    // cs: reduce over the 4 quads (rows) -> lanes 0..15 hold col partials
    #pragma unroll
    for (int t = 0; t < 8; ++t) {
        float v = cs[t];
        v += __shfl_xor(v, 16, 64);
        v += __shfl_xor(v, 32, 64);
        if (q == 0) cs_p[w][t * 16 + l15] = v;
    }
    __syncthreads();

    // coalesced 512 B stores into block-private slice runs
    if (tid < 128) {
        spart[(size_t)tj * NROW + ti * 128 + tid] = rs_t[tid];
    } else if (!isDiag) {
        int c = tid - 128;
        float v = cs_p[0][c] + cs_p[1][c] + cs_p[2][c] + cs_p[3][c];
        spart[(size_t)ti * NROW + tj * 128 + c] = v;
    }
}

// ------------- Kernel 4: per-row finalize (wave per row, 2048 blocks) ------
__global__ void k_finalize(const unsigned* __restrict__ pnh, const float* __restrict__ spart,
                           const float* __restrict__ g, const float* __restrict__ cnt,
                           const int* __restrict__ y, float* __restrict__ partial) {
    __shared__ float red[4];
    int tid = threadIdx.x, wv = tid >> 6, lane = tid & 63;
    int row = blockIdx.x * 4 + wv;
    int lab = y[row & (BSZ - 1)];
    unsigned u = pnh[(size_t)row * 64 + lane];
    float p0 = __uint_as_float(u << 16);
    float p1 = __uint_as_float(u & 0xFFFF0000u);
    float2 gv = ((const float2*)(g + lab * DIM))[lane];
    float dg = p0 * gv.x + p1 * gv.y;
    float ds = p0 * p0 + p1 * p1;
    float sp = spart[(size_t)lane * NROW + row];   // lane = slice (L2-resident)
    #pragma unroll
    for (int m = 32; m; m >>= 1) {
        dg += __shfl_xor(dg, m, 64);
        ds += __shfl_xor(ds, m, 64);
        sp += __shfl_xor(sp, m, 64);
    }
    if (lane == 0) {
        float C = cnt[lab] - 1.0f;           // pos count excludes self
        float P = (dg - ds) * 10.0f;         // sum of sims over positives
        red[wv] = logf(sp) - P / C;          // -(mean log prob pos)
    }
    __syncthreads();
    if (tid == 0) partial[blockIdx.x] = red[0] + red[1] + red[2] + red[3];
}

// --------------------- Kernel 5: final reduce of 2048 ----------------------
__global__ void k_sum(const float* __restrict__ partial, float* __restrict__ out) {
    __shared__ float red[256];
    float v = 0.f;
    #pragma unroll
    for (int i = 0; i < 8; ++i) v += partial[threadIdx.x + 256 * i];
    red[threadIdx.x] = v;
    __syncthreads();
    for (int s = 128; s; s >>= 1) {
        if (threadIdx.x < s) red[threadIdx.x] += red[threadIdx.x + s];
        __syncthreads();
    }
    if (threadIdx.x == 0) out[0] = red[0];
}

extern "C" void kernel_launch(void* const* d_in, const int* in_sizes, int n_in,
                              void* d_out, int out_size, void* d_ws, size_t ws_size,
                              hipStream_t stream) {
    const float* zi = (const float*)d_in[0];
    const float* zj = (const float*)d_in[1];
    const int*   y  = (const int*)d_in[2];
    float* out = (float*)d_out;
    float* ws  = (float*)d_ws;

    unsigned* pnh  = (unsigned*)ws;                 // linear, unscaled
    unsigned* pnsw = (unsigned*)(ws + PNH_F);       // swizzled, x sqrt(10/ln2)
    float* g       = ws + G_OFF;
    float* cnt     = ws + CNT_OFF;
    float* spart   = ws + SPART_OFF;
    float* partial = ws + PART_OFF;

    k_norm<<<NROW / 4, 256, 0, stream>>>(zi, zj, pnh, pnsw, g);
    k_colsum<<<129, 256, 0, stream>>>(pnh, y, g, cnt);
    k_expsum<<<2080, 256, 0, stream>>>((const unsigned short*)pnsw, spart);
    k_finalize<<<NROW / 4, 256, 0, stream>>>(pnh, spart, g, cnt, y, partial);
    k_sum<<<1, 256, 0, stream>>>(partial, out);
}